// Round 7
// baseline (206.313 us; speedup 1.0000x reference)
//
#include <hip/hip_runtime.h>

#define SEQ 4096
#define DIM 64
#define CHUNK 128
#define NC 32
#define EPSV 1e-10f
#define KS_OFF 2097152   // float offset of ksum region (S region = 1024 chunks * 4096 bf16 = 8 MiB)
#define FLAG_OFF (KS_OFF + 65536)   // float offset of 512 lookback flags (zeroed per launch)

typedef __attribute__((ext_vector_type(8))) short s16x8;   // 8 bf16 (4 VGPRs)
typedef __attribute__((ext_vector_type(4))) float f32x4;   // MFMA C/D

__device__ __forceinline__ unsigned short f2bf(float f) {
  unsigned int u = __float_as_uint(f);
  u += 0x7FFF + ((u >> 16) & 1);          // RNE (inputs are finite)
  return (unsigned short)(u >> 16);
}

// native packed f32->bf16 (RNE), src0 -> low16, src1 -> high16
__device__ __forceinline__ unsigned int cvtpk(float lo, float hi) {
  unsigned int r;
  asm("v_cvt_pk_bf16_f32 %0, %1, %2" : "=v"(r) : "v"(lo), "v"(hi));
  return r;
}
__device__ __forceinline__ s16x8 pack8(float4 a, float4 b) {
  union { unsigned int u[4]; s16x8 v; } r;
  r.u[0] = cvtpk(a.x, a.y); r.u[1] = cvtpk(a.z, a.w);
  r.u[2] = cvtpk(b.x, b.y); r.u[3] = cvtpk(b.z, b.w);
  return r.v;
}

// XCD-bijective swizzle for 512 blocks (8 XCDs x 64): same (hh) group stays on one XCD.
__device__ __forceinline__ int swz512(int b) { return ((b & 7) << 6) | (b >> 3); }

// agent-scope (cross-XCD coherent) primitives for the lookback protocol
__device__ __forceinline__ void flag_store(float* p) {
  __hip_atomic_store((unsigned int*)p, 1u, __ATOMIC_RELEASE, __HIP_MEMORY_SCOPE_AGENT);
}
__device__ __forceinline__ unsigned int flag_load(const float* p) {
  return __hip_atomic_load((const unsigned int*)p, __ATOMIC_RELAXED, __HIP_MEMORY_SCOPE_AGENT);
}
__device__ __forceinline__ unsigned long long ld64_agent(const unsigned long long* p) {
  return __hip_atomic_load(p, __ATOMIC_RELAXED, __HIP_MEMORY_SCOPE_AGENT);
}
__device__ __forceinline__ float ldf_agent(const float* p) {
  unsigned int x = __hip_atomic_load((const unsigned int*)p, __ATOMIC_RELAXED, __HIP_MEMORY_SCOPE_AGENT);
  return __uint_as_float(x);
}

// Coalesced transposed gather: global [128][64] f32 row-major -> LDS T[d][j] bf16, stride 136.
template<bool SUM, int TPB>
__device__ __forceinline__ float gather_T(const float* __restrict__ gp,
                                          unsigned short* __restrict__ dst, int t) {
  int d = t & 63, grp = t >> 6;
  constexpr int GRPS = TPB / 64;
  constexpr int NI = 16 / GRPS;
  float s = 0.f;
#pragma unroll
  for (int i = 0; i < NI; ++i) {
    int j8 = grp + i * GRPS;
    const float* p = gp + (size_t)(j8 * 8) * DIM + d;
    float x[8];
#pragma unroll
    for (int u2 = 0; u2 < 8; ++u2) x[u2] = p[(size_t)u2 * DIM];
    if (SUM) {
#pragma unroll
      for (int u2 = 0; u2 < 8; ++u2) s += x[u2];
    }
    union { unsigned int u4[4]; s16x8 v; } seg;
#pragma unroll
    for (int u2 = 0; u2 < 4; ++u2) seg.u4[u2] = cvtpk(x[2 * u2], x[2 * u2 + 1]);
    *(s16x8*)&dst[d * 136 + j8 * 8] = seg.v;
  }
  return s;
}

// ================= Fused single kernel =================
// Phase 1 (= verified pass_a body): gather kT/vT, MFMA S_c, publish S_c bf16 + ksum_c fp32,
// then release a per-block flag (in ws, zeroed via stream-ordered memset each launch).
// Lookback: spin on predecessor flags (all 512 blocks co-resident at 2/CU; wait-graph is
// topologically ordered by block id, so no deadlock even under partial residency), then
// fp32-accumulate the c predecessor aggregates (bit-identical to old pass_b numerics).
// Phase C (= verified round-2/5 pass_c body): svT persists from phase 1 (no re-gather).
__global__ __launch_bounds__(512, 4) void fused(const float* __restrict__ q0,
                                                const float* __restrict__ q1,
                                                const float* __restrict__ k0,
                                                const float* __restrict__ k1,
                                                const float* __restrict__ v,
                                                float* __restrict__ ws,
                                                float* __restrict__ out) {
  __shared__ __align__(16) unsigned short svT[64 * 136];   // vT[e][j], phase1 -> phaseC
  __shared__ float sden[2][128];
  __shared__ __align__(16) union UB {
    struct { unsigned short skT[2][64 * 136]; float spart[2][4][64]; } a;  // phase 1
    struct { unsigned short sST[2][64 * 72]; float skpref[2][64]; } c1;    // phase C stage
    float exch[128 * 66];                                                  // phase C epilogue
  } u;

  int bid = swz512(blockIdx.x);
  int hh = bid >> 5, c = bid & 31;
  int t = threadIdx.x, half = t >> 8, tt = t & 255;
  size_t off = (size_t)hh * SEQ * DIM + (size_t)c * CHUNK * DIM;
  int chunk = half * 512 + hh * 32 + c;
  float* flags = ws + FLAG_OFF + (size_t)hh * 32;   // flags[cc], cc in [0,32)

  // ---- phase 1: gathers ----
  const float* kp = (half ? k1 : k0) + off;
  float s = gather_T<true, 256>(kp, u.a.skT[half], tt);
  gather_T<false, 512>(v + off, svT, t);
  u.a.spart[half][tt >> 6][tt & 63] = s;
  __syncthreads();

  // ksum_c publish (fp32, pre-rounding values)
  if (tt < 64)
    ws[KS_OFF + (size_t)chunk * 64 + tt] = u.a.spart[half][0][tt] + u.a.spart[half][1][tt]
                                         + u.a.spart[half][2][tt] + u.a.spart[half][3][tt];

  // MFMA S_c: wave wv (within half) -> e-tile wv; A = vT, B = kT
  {
    int wv = tt >> 6, Lp = tt & 63, gp2 = Lp >> 4, cLp = Lp & 15;
    f32x4 acc[4];
#pragma unroll
    for (int ct = 0; ct < 4; ++ct) acc[ct] = (f32x4){0.f, 0.f, 0.f, 0.f};
#pragma unroll
    for (int ks = 0; ks < 4; ++ks) {
      s16x8 aF = *(const s16x8*)&svT[(wv * 16 + cLp) * 136 + ks * 32 + gp2 * 8];
#pragma unroll
      for (int ct = 0; ct < 4; ++ct) {
        s16x8 bF = *(const s16x8*)&u.a.skT[half][(ct * 16 + cLp) * 136 + ks * 32 + gp2 * 8];
        acc[ct] = __builtin_amdgcn_mfma_f32_16x16x32_bf16(aF, bF, acc[ct], 0, 0, 0);
      }
    }
    unsigned short* Sp = (unsigned short*)ws + (size_t)chunk * 4096;
#pragma unroll
    for (int ct = 0; ct < 4; ++ct)
#pragma unroll
      for (int r = 0; r < 4; ++r)
        Sp[(size_t)(wv * 16 + gp2 * 4 + r) * 64 + ct * 16 + cLp] = f2bf(acc[ct][r]);
  }

  __syncthreads();                        // vmcnt(0): all S/ksum stores left the CU
  if (t == 0) {
    __threadfence();                      // L2 writeback -> LLC: visible cross-XCD
    flag_store(&flags[c]);
  }

  int w = t >> 6, L = t & 63, g = L >> 4, cL = L & 15;
  const int rtS0 = w, rtS1 = 7 - w;

  // ---- lookback: wait for predecessors, then parallel aggregate ----
  if (c > 0) {
    if (w == 0 && L < c) {
      while (flag_load(&flags[L]) == 0u) __builtin_amdgcn_s_sleep(2);
    }
    __syncthreads();
  }
  {
    int cb = half * 512 + hh * 32;
    const unsigned long long* S64 = (const unsigned long long*)ws;
    float aS[16];
#pragma unroll
    for (int i = 0; i < 16; ++i) aS[i] = 0.f;
    for (int cc = 0; cc < c; ++cc) {
      const unsigned long long* p = S64 + (size_t)(cb + cc) * 1024 + tt * 4;
#pragma unroll
      for (int qd = 0; qd < 4; ++qd) {
        unsigned long long q = ld64_agent(p + qd);
        unsigned int d0 = (unsigned int)q, d1 = (unsigned int)(q >> 32);
        aS[4 * qd + 0] += __uint_as_float(d0 << 16);
        aS[4 * qd + 1] += __uint_as_float(d0 & 0xFFFF0000u);
        aS[4 * qd + 2] += __uint_as_float(d1 << 16);
        aS[4 * qd + 3] += __uint_as_float(d1 & 0xFFFF0000u);
      }
    }
    union { unsigned int u4[4]; s16x8 v8; } w0, w1;
#pragma unroll
    for (int i = 0; i < 4; ++i) w0.u4[i] = cvtpk(aS[2 * i], aS[2 * i + 1]);
#pragma unroll
    for (int i = 0; i < 4; ++i) w1.u4[i] = cvtpk(aS[8 + 2 * i], aS[8 + 2 * i + 1]);
    int i0 = 2 * tt, i1 = 2 * tt + 1;     // 8-short group indices (verified mapping)
    *(s16x8*)&u.c1.sST[half][(i0 >> 3) * 72 + (i0 & 7) * 8] = w0.v8;
    *(s16x8*)&u.c1.sST[half][(i1 >> 3) * 72 + (i1 & 7) * 8] = w1.v8;
    if (tt < 64) {
      float run = 0.f;
      for (int cc = 0; cc < c; ++cc)
        run += ldf_agent(&ws[KS_OFF + (size_t)(cb + cc) * 64 + tt]);
      u.c1.skpref[half][tt] = run;
    }
  }
  __syncthreads();

  // ---- phase C (verified body) ----
  f32x4 accO[2][4];
#pragma unroll
  for (int a = 0; a < 2; ++a)
#pragma unroll
    for (int b = 0; b < 4; ++b) accO[a][b] = (f32x4){0.f, 0.f, 0.f, 0.f};
  float dent[2] = {0.f, 0.f};
  s16x8 aq[2][2];

  // q loads + den(q . ksum_prefix) + inter O += q @ S_prefix
#pragma unroll
  for (int s2 = 0; s2 < 2; ++s2) {
    int rt = s2 ? rtS1 : rtS0;
    const float* qp = (s2 ? q1 : q0) + off;
    int row = rt * 16 + cL;
#pragma unroll
    for (int h = 0; h < 2; ++h) {
      const float* qb = qp + (size_t)row * DIM + h * 32 + g * 8;
      float4 a0 = *(const float4*)qb;
      float4 a1 = *(const float4*)(qb + 4);
      const float* kq = &u.c1.skpref[s2][h * 32 + g * 8];
      dent[s2] += a0.x * kq[0] + a0.y * kq[1] + a0.z * kq[2] + a0.w * kq[3]
                + a1.x * kq[4] + a1.y * kq[5] + a1.z * kq[6] + a1.w * kq[7];
      aq[s2][h] = pack8(a0, a1);
    }
#pragma unroll
    for (int h = 0; h < 2; ++h)
#pragma unroll
      for (int et = 0; et < 4; ++et) {
        s16x8 bS = *(const s16x8*)&u.c1.sST[s2][(et * 16 + cL) * 72 + h * 32 + g * 8];
        accO[s2][et] = __builtin_amdgcn_mfma_f32_16x16x32_bf16(aq[s2][h], bS, accO[s2][et], 0, 0, 0);
      }
  }

  // QK^T (swapped operands -> P^T) + in-register transpose + PV
  {
    int srcA = cL + ((g & 1) << 5), srcB = srcA + 16;
    bool hiG = g >= 2;
#pragma unroll
    for (int s2 = 0; s2 < 2; ++s2) {
      int rt = s2 ? rtS1 : rtS0;
      const float* kpp = (s2 ? k1 : k0) + off;
      for (int ks = 0; ks <= (rt >> 1); ++ks) {
        unsigned int E0e, E1e;
        {
          int jt = 2 * ks;
          const float* kb = kpp + (size_t)(jt * 16 + cL) * DIM;
          float4 b0 = *(const float4*)(kb + g * 8);
          float4 b1 = *(const float4*)(kb + g * 8 + 4);
          float4 b2 = *(const float4*)(kb + 32 + g * 8);
          float4 b3 = *(const float4*)(kb + 32 + g * 8 + 4);
          s16x8 kf0 = pack8(b0, b1), kf1 = pack8(b2, b3);
          f32x4 C = (f32x4){0.f, 0.f, 0.f, 0.f};
          C = __builtin_amdgcn_mfma_f32_16x16x32_bf16(kf0, aq[s2][0], C, 0, 0, 0);
          C = __builtin_amdgcn_mfma_f32_16x16x32_bf16(kf1, aq[s2][1], C, 0, 0, 0);
          if (jt == rt) {
#pragma unroll
            for (int r = 0; r < 4; ++r)
              if (g * 4 + r > cL) C[r] = 0.f;
          }
          dent[s2] += C[0] + C[1] + C[2] + C[3];
          E0e = cvtpk(C[0], C[1]); E1e = cvtpk(C[2], C[3]);
        }
        int S0o = 0, S1o = 0, S2o = 0, S3o = 0;
        if (2 * ks + 1 <= rt) {
          int jt = 2 * ks + 1;
          const float* kb = kpp + (size_t)(jt * 16 + cL) * DIM;
          float4 b0 = *(const float4*)(kb + g * 8);
          float4 b1 = *(const float4*)(kb + g * 8 + 4);
          float4 b2 = *(const float4*)(kb + 32 + g * 8);
          float4 b3 = *(const float4*)(kb + 32 + g * 8 + 4);
          s16x8 kf0 = pack8(b0, b1), kf1 = pack8(b2, b3);
          f32x4 C = (f32x4){0.f, 0.f, 0.f, 0.f};
          C = __builtin_amdgcn_mfma_f32_16x16x32_bf16(kf0, aq[s2][0], C, 0, 0, 0);
          C = __builtin_amdgcn_mfma_f32_16x16x32_bf16(kf1, aq[s2][1], C, 0, 0, 0);
          if (jt == rt) {
#pragma unroll
            for (int r = 0; r < 4; ++r)
              if (g * 4 + r > cL) C[r] = 0.f;
          }
          dent[s2] += C[0] + C[1] + C[2] + C[3];
          unsigned int E0o = cvtpk(C[0], C[1]), E1o = cvtpk(C[2], C[3]);
          S0o = __shfl((int)E0o, srcA); S1o = __shfl((int)E1o, srcA);
          S2o = __shfl((int)E0o, srcB); S3o = __shfl((int)E1o, srcB);
        }
        int S0e = __shfl((int)E0e, srcA); int S1e = __shfl((int)E1e, srcA);
        int S2e = __shfl((int)E0e, srcB); int S3e = __shfl((int)E1e, srcB);
        union { int d4[4]; s16x8 v8; } ap;
        ap.d4[0] = hiG ? S0o : S0e;
        ap.d4[1] = hiG ? S1o : S1e;
        ap.d4[2] = hiG ? S2o : S2e;
        ap.d4[3] = hiG ? S3o : S3e;
#pragma unroll
        for (int et = 0; et < 4; ++et) {
          s16x8 bV = *(const s16x8*)&svT[(et * 16 + cL) * 136 + ks * 32 + g * 8];
          accO[s2][et] = __builtin_amdgcn_mfma_f32_16x16x32_bf16(ap.v8, bV, accO[s2][et], 0, 0, 0);
        }
      }
    }
  }

  // den: reduce over g, publish per row/m
#pragma unroll
  for (int s2 = 0; s2 < 2; ++s2) {
    float dt = dent[s2];
    dt += __shfl_xor(dt, 16);
    dt += __shfl_xor(dt, 32);
    dent[s2] = dt;
  }
  if (L < 16) {
    sden[0][rtS0 * 16 + L] = dent[0];
    sden[1][rtS1 * 16 + L] = dent[1];
  }
  __syncthreads();

  // publish m1 accO into exchange
#pragma unroll
  for (int et = 0; et < 4; ++et)
#pragma unroll
    for (int r = 0; r < 4; ++r)
      u.exch[(rtS1 * 16 + g * 4 + r) * 66 + et * 16 + cL] = accO[1][et][r];
  __syncthreads();

  // finalize
  float* op = out + off;
#pragma unroll
  for (int r = 0; r < 4; ++r) {
    int row = rtS0 * 16 + g * 4 + r;
    float inv = 1.f / (sden[0][row] + sden[1][row] + EPSV);
#pragma unroll
    for (int et = 0; et < 4; ++et) {
      float O = accO[0][et][r] + u.exch[row * 66 + et * 16 + cL];
      op[(size_t)row * DIM + et * 16 + cL] = O * inv;
    }
  }
}

extern "C" void kernel_launch(void* const* d_in, const int* in_sizes, int n_in,
                              void* d_out, int out_size, void* d_ws, size_t ws_size,
                              hipStream_t stream) {
  const float* q  = (const float*)d_in[0];
  const float* k  = (const float*)d_in[1];
  const float* qr = (const float*)d_in[2];
  const float* kr = (const float*)d_in[3];
  const float* v  = (const float*)d_in[4];
  float* out = (float*)d_out;
  float* ws  = (float*)d_ws;

  // zero the 512 lookback flags (stream-ordered, graph-capture-safe memset node)
  hipMemsetAsync(ws + FLAG_OFF, 0, 512 * sizeof(float), stream);
  hipLaunchKernelGGL(fused, dim3(512), dim3(512), 0, stream, q, qr, k, kr, v, ws, out);
}

// Round 8
// 145.890 us; speedup vs baseline: 1.4142x; 1.4142x over previous
//
#include <hip/hip_runtime.h>

#define SEQ 4096
#define DIM 64
#define CHUNK 128
#define NC 32
#define EPSV 1e-10f
#define KS_OFF 2097152   // float offset of ksum region (S region = 1024 chunks * 4096 bf16 = 8 MiB)
#define KB_OFF 2162688   // float offset of bf16 k copy (1024 chunk-m * 8192 shorts = 16 MiB)
#define VB_OFF 6356992   // float offset of bf16 vT copy (512 chunks * 8192 shorts = 8 MiB)

typedef __attribute__((ext_vector_type(8))) short s16x8;   // 8 bf16 (4 VGPRs)
typedef __attribute__((ext_vector_type(4))) float f32x4;   // MFMA C/D

__device__ __forceinline__ unsigned short f2bf(float f) {
  unsigned int u = __float_as_uint(f);
  u += 0x7FFF + ((u >> 16) & 1);          // RNE (inputs are finite)
  return (unsigned short)(u >> 16);
}
__device__ __forceinline__ float bf2f_lo(unsigned int x) { return __uint_as_float(x << 16); }

// native packed f32->bf16 (RNE), src0 -> low16, src1 -> high16
__device__ __forceinline__ unsigned int cvtpk(float lo, float hi) {
  unsigned int r;
  asm("v_cvt_pk_bf16_f32 %0, %1, %2" : "=v"(r) : "v"(lo), "v"(hi));
  return r;
}
__device__ __forceinline__ s16x8 pack8(float4 a, float4 b) {
  union { unsigned int u[4]; s16x8 v; } r;
  r.u[0] = cvtpk(a.x, a.y); r.u[1] = cvtpk(a.z, a.w);
  r.u[2] = cvtpk(b.x, b.y); r.u[3] = cvtpk(b.z, b.w);
  return r.v;
}

// Coalesced transposed gather: global [128][64] f32 row-major -> LDS T[d][j] bf16, stride 136.
template<bool SUM, int TPB>
__device__ __forceinline__ float gather_T(const float* __restrict__ gp,
                                          unsigned short* __restrict__ dst, int t) {
  int d = t & 63, grp = t >> 6;
  constexpr int GRPS = TPB / 64;
  constexpr int NI = 16 / GRPS;
  float s = 0.f;
#pragma unroll
  for (int i = 0; i < NI; ++i) {
    int j8 = grp + i * GRPS;
    const float* p = gp + (size_t)(j8 * 8) * DIM + d;
    float x[8];
#pragma unroll
    for (int u2 = 0; u2 < 8; ++u2) x[u2] = p[(size_t)u2 * DIM];
    if (SUM) {
#pragma unroll
      for (int u2 = 0; u2 < 8; ++u2) s += x[u2];
    }
    union { unsigned int u4[4]; s16x8 v; } seg;
#pragma unroll
    for (int u2 = 0; u2 < 4; ++u2) seg.u4[u2] = cvtpk(x[2 * u2], x[2 * u2 + 1]);
    *(s16x8*)&dst[d * 136 + j8 * 8] = seg.v;
  }
  return s;
}

// ---------------- Pass A: S^T via MFMA; also export bf16 k (row-major) + bf16 vT ----------------
// 1024 blocks x 256 threads = 4 blocks/CU (LDS 35.8 KB) — measured faster than 512x512 variant.
__global__ __launch_bounds__(256, 4) void pass_a(const float* __restrict__ k0,
                                                 const float* __restrict__ k1,
                                                 const float* __restrict__ v,
                                                 float* __restrict__ ws) {
  __shared__ __align__(16) unsigned short skT[64 * 136];   // kT[d][j]
  __shared__ __align__(16) unsigned short svT[64 * 136];   // vT[e][j]
  __shared__ float spart[4][64];                           // fp32 ksum partials
  int bid = blockIdx.x;
  int m = bid >> 9, rem = bid & 511, hh = rem >> 5, c = rem & 31;
  size_t off = (size_t)hh * SEQ * DIM + (size_t)c * CHUNK * DIM;
  const float* kp = (m ? k1 : k0) + off;
  const float* vp = v + off;
  int t = threadIdx.x;
  int chunk = m * 512 + rem;

  float s = gather_T<true, 256>(kp, skT, t);
  gather_T<false, 256>(vp, svT, t);
  spart[t >> 6][t & 63] = s;
  __syncthreads();

  // ksum[d] in full fp32 (pre-rounding values)
  if (t < 64)
    ws[KS_OFF + (size_t)chunk * 64 + t] = spart[0][t] + spart[1][t] + spart[2][t] + spart[3][t];

  // MFMA: wave w -> e-tile w; A = vT (m=e), B = kT rows (k=j, n=d)
  int w = t >> 6, L = t & 63, g = L >> 4, cL = L & 15;
  f32x4 acc[4];
#pragma unroll
  for (int ct = 0; ct < 4; ++ct) acc[ct] = (f32x4){0.f, 0.f, 0.f, 0.f};
#pragma unroll
  for (int ks = 0; ks < 4; ++ks) {
    s16x8 aF = *(const s16x8*)&svT[(w * 16 + cL) * 136 + ks * 32 + g * 8];
#pragma unroll
    for (int ct = 0; ct < 4; ++ct) {
      s16x8 bF = *(const s16x8*)&skT[(ct * 16 + cL) * 136 + ks * 32 + g * 8];
      acc[ct] = __builtin_amdgcn_mfma_f32_16x16x32_bf16(aF, bF, acc[ct], 0, 0, 0);
    }
  }
  // C/D layout: col = cL (=d-local), row = g*4+r (=e-local); store bf16
  unsigned short* Sp = (unsigned short*)ws + (size_t)chunk * 4096;
#pragma unroll
  for (int ct = 0; ct < 4; ++ct)
#pragma unroll
    for (int r = 0; r < 4; ++r)
      Sp[(size_t)(w * 16 + g * 4 + r) * 64 + ct * 16 + cL] = f2bf(acc[ct][r]);

  // export k as bf16 row-major (linear L2-hot re-read, coalesced store; same RNE as pack8)
  {
    unsigned short* kb16 = (unsigned short*)(ws + KB_OFF) + (size_t)chunk * 8192;
#pragma unroll
    for (int p2 = 0; p2 < 2; ++p2) {
      int idx = t + p2 * 256;                  // 512 segments x 16 floats
      const float* src = kp + (size_t)idx * 16;
      float4 x0 = *(const float4*)src;
      float4 x1 = *(const float4*)(src + 4);
      float4 x2 = *(const float4*)(src + 8);
      float4 x3 = *(const float4*)(src + 12);
      *(s16x8*)&kb16[(size_t)idx * 16] = pack8(x0, x1);
      *(s16x8*)&kb16[(size_t)idx * 16 + 8] = pack8(x2, x3);
    }
  }
  // export vT bf16 in pass_c's LDS layout, packed rows of 128 shorts (m==0 blocks only)
  if (m == 0) {
    unsigned short* vb16 = (unsigned short*)(ws + VB_OFF) + (size_t)rem * 8192;
#pragma unroll
    for (int p2 = 0; p2 < 4; ++p2) {
      int idx = t + p2 * 256;                  // [0,1024): d = idx>>4, seg = idx&15
      *(s16x8*)&vb16[(size_t)idx * 8] = *(const s16x8*)&svT[(idx >> 4) * 136 + (idx & 15) * 8];
    }
  }
}

// ---------------- Pass B: exclusive prefix over chunks; all 32 loads in flight ----------------
__global__ __launch_bounds__(256) void pass_b(float* __restrict__ ws) {
  int t = threadIdx.x;
  if (blockIdx.x < 256) {
    int gid = blockIdx.x * 256 + t;            // [0, 65536)
    int mh = gid >> 11, de2 = gid & 2047;      // mh in [0,32)
    unsigned int* p = (unsigned int*)ws + (size_t)mh * NC * 2048 + de2;
    unsigned int x[NC];
#pragma unroll
    for (int c = 0; c < NC; ++c) x[c] = p[(size_t)c * 2048];
    float r0 = 0.f, r1 = 0.f;
#pragma unroll
    for (int c = 0; c < NC; ++c) {
      unsigned int xc = x[c];
      p[(size_t)c * 2048] = (unsigned int)f2bf(r0) | ((unsigned int)f2bf(r1) << 16);
      r0 += bf2f_lo(xc & 0xFFFFu);
      r1 += __uint_as_float(xc & 0xFFFF0000u);
    }
  } else {
    int gid = (blockIdx.x - 256) * 256 + t;    // [0, 2048)
    int mh = gid >> 6, d = gid & 63;
    float* p = ws + KS_OFF + (size_t)mh * NC * 64 + d;
    float x[NC];
#pragma unroll
    for (int c = 0; c < NC; ++c) x[c] = p[(size_t)c * 64];
    float run = 0.f;
#pragma unroll
    for (int c = 0; c < NC; ++c) {
      p[(size_t)c * 64] = run;
      run += x[c];
    }
  }
}

// ---------------- Pass C: per-chunk output via MFMA, 8 waves, m-parallel ----------------
// v staged by LINEAR bf16 copy (no strided gather, no cvt); QK B-frags loaded directly as
// bf16 from the pass_a export (no fp32 re-read, no re-pack). Numerically bit-identical.
__global__ __launch_bounds__(512, 4) void pass_c(const float* __restrict__ q0,
                                                 const float* __restrict__ q1,
                                                 const float* __restrict__ ws,
                                                 float* __restrict__ out) {
  __shared__ __align__(16) unsigned short svT[64 * 136];   // vT[e][j]  17408 B
  __shared__ __align__(16) union UBuf {
    struct {
      unsigned short sST[2][64 * 72];                      // S^T prefix per m, 18432 B
      float skpref[2][64];                                 // 512 B
    } a;
    float exch[128 * 66];                                  // m1 accO exchange, 33792 B
  } u;
  __shared__ float sden[2][128];

  int hh = blockIdx.x >> 5, c = blockIdx.x & 31;
  int t = threadIdx.x;
  int w = t >> 6, L = t & 63, g = L >> 4, cL = L & 15;
  int half = t >> 8, tt = t & 255;
  size_t off = (size_t)hh * SEQ * DIM + (size_t)c * CHUNK * DIM;
  const int rtS0 = w, rtS1 = 7 - w;

  // v stage: linear 16B copy into the transposed LDS layout
  {
    const unsigned short* vb16 = (const unsigned short*)(ws + VB_OFF) + (size_t)(hh * 32 + c) * 8192;
#pragma unroll
    for (int p2 = 0; p2 < 2; ++p2) {
      int idx = t + p2 * 512;                  // [0,1024): d = idx>>4, seg = idx&15
      *(s16x8*)&svT[(idx >> 4) * 136 + (idx & 15) * 8] = *(const s16x8*)&vb16[(size_t)idx * 8];
    }
  }
  // stage S^T prefix (bf16) + ksum-prefix for both m: half-block each
  {
    const unsigned short* Sp = (const unsigned short*)ws + (size_t)(half * 512 + hh * 32 + c) * 4096;
    const float* Kp = ws + KS_OFF + (size_t)(half * 512 + hh * 32 + c) * 64;
#pragma unroll
    for (int p2 = 0; p2 < 2; ++p2) {
      int idx = tt + p2 * 256;
      *(s16x8*)&u.a.sST[half][(idx >> 3) * 72 + (idx & 7) * 8] = *(const s16x8*)&Sp[idx * 8];
    }
    if (tt < 64) u.a.skpref[half][tt] = Kp[tt];
  }
  __syncthreads();

  f32x4 accO[2][4];
#pragma unroll
  for (int a = 0; a < 2; ++a)
#pragma unroll
    for (int b = 0; b < 4; ++b) accO[a][b] = (f32x4){0.f, 0.f, 0.f, 0.f};
  float dent[2] = {0.f, 0.f};
  s16x8 aq[2][2];

  // q loads + den(q . ksum_prefix) + inter O += q @ S_prefix
#pragma unroll
  for (int s2 = 0; s2 < 2; ++s2) {
    int rt = s2 ? rtS1 : rtS0;
    const float* qp = (s2 ? q1 : q0) + off;
    int row = rt * 16 + cL;
#pragma unroll
    for (int h = 0; h < 2; ++h) {
      const float* qb = qp + (size_t)row * DIM + h * 32 + g * 8;
      float4 a0 = *(const float4*)qb;
      float4 a1 = *(const float4*)(qb + 4);
      const float* kq = &u.a.skpref[s2][h * 32 + g * 8];
      dent[s2] += a0.x * kq[0] + a0.y * kq[1] + a0.z * kq[2] + a0.w * kq[3]
                + a1.x * kq[4] + a1.y * kq[5] + a1.z * kq[6] + a1.w * kq[7];
      aq[s2][h] = pack8(a0, a1);
    }
#pragma unroll
    for (int h = 0; h < 2; ++h)
#pragma unroll
      for (int et = 0; et < 4; ++et) {
        s16x8 bS = *(const s16x8*)&u.a.sST[s2][(et * 16 + cL) * 72 + h * 32 + g * 8];
        accO[s2][et] = __builtin_amdgcn_mfma_f32_16x16x32_bf16(aq[s2][h], bS, accO[s2][et], 0, 0, 0);
      }
  }

  // QK^T (swapped operands -> P^T: col=i=cL, row=j=g*4+r) + in-register transpose + PV
  {
    int srcA = cL + ((g & 1) << 5), srcB = srcA + 16;
    bool hiG = g >= 2;
#pragma unroll
    for (int s2 = 0; s2 < 2; ++s2) {
      int rt = s2 ? rtS1 : rtS0;
      const unsigned short* kb16 = (const unsigned short*)(ws + KB_OFF)
                                 + (size_t)(s2 * 512 + hh * 32 + c) * 8192;
      for (int ks = 0; ks <= (rt >> 1); ++ks) {
        unsigned int E0e, E1e;
        {
          int jt = 2 * ks;
          int row = jt * 16 + cL;
          s16x8 kf0 = *(const s16x8*)&kb16[(size_t)row * 64 + g * 8];
          s16x8 kf1 = *(const s16x8*)&kb16[(size_t)row * 64 + 32 + g * 8];
          f32x4 C = (f32x4){0.f, 0.f, 0.f, 0.f};
          C = __builtin_amdgcn_mfma_f32_16x16x32_bf16(kf0, aq[s2][0], C, 0, 0, 0);
          C = __builtin_amdgcn_mfma_f32_16x16x32_bf16(kf1, aq[s2][1], C, 0, 0, 0);
          if (jt == rt) {                      // diagonal: zero j>i -> (g*4+r) > cL
#pragma unroll
            for (int r = 0; r < 4; ++r)
              if (g * 4 + r > cL) C[r] = 0.f;
          }
          dent[s2] += C[0] + C[1] + C[2] + C[3];
          E0e = cvtpk(C[0], C[1]); E1e = cvtpk(C[2], C[3]);
        }
        int S0o = 0, S1o = 0, S2o = 0, S3o = 0;
        if (2 * ks + 1 <= rt) {                // odd tile present (wave-uniform)
          int jt = 2 * ks + 1;
          int row = jt * 16 + cL;
          s16x8 kf0 = *(const s16x8*)&kb16[(size_t)row * 64 + g * 8];
          s16x8 kf1 = *(const s16x8*)&kb16[(size_t)row * 64 + 32 + g * 8];
          f32x4 C = (f32x4){0.f, 0.f, 0.f, 0.f};
          C = __builtin_amdgcn_mfma_f32_16x16x32_bf16(kf0, aq[s2][0], C, 0, 0, 0);
          C = __builtin_amdgcn_mfma_f32_16x16x32_bf16(kf1, aq[s2][1], C, 0, 0, 0);
          if (jt == rt) {
#pragma unroll
            for (int r = 0; r < 4; ++r)
              if (g * 4 + r > cL) C[r] = 0.f;
          }
          dent[s2] += C[0] + C[1] + C[2] + C[3];
          unsigned int E0o = cvtpk(C[0], C[1]), E1o = cvtpk(C[2], C[3]);
          S0o = __shfl((int)E0o, srcA); S1o = __shfl((int)E1o, srcA);
          S2o = __shfl((int)E0o, srcB); S3o = __shfl((int)E1o, srcB);
        }
        int S0e = __shfl((int)E0e, srcA); int S1e = __shfl((int)E1e, srcA);
        int S2e = __shfl((int)E0e, srcB); int S3e = __shfl((int)E1e, srcB);
        union { int d4[4]; s16x8 v8; } ap;
        ap.d4[0] = hiG ? S0o : S0e;
        ap.d4[1] = hiG ? S1o : S1e;
        ap.d4[2] = hiG ? S2o : S2e;
        ap.d4[3] = hiG ? S3o : S3e;
#pragma unroll
        for (int et = 0; et < 4; ++et) {
          s16x8 bV = *(const s16x8*)&svT[(et * 16 + cL) * 136 + ks * 32 + g * 8];
          accO[s2][et] = __builtin_amdgcn_mfma_f32_16x16x32_bf16(ap.v8, bV, accO[s2][et], 0, 0, 0);
        }
      }
    }
  }

  // den: reduce over g (full j and d coverage for row i=cL), publish per row/m
#pragma unroll
  for (int s2 = 0; s2 < 2; ++s2) {
    float dt = dent[s2];
    dt += __shfl_xor(dt, 16);
    dt += __shfl_xor(dt, 32);
    dent[s2] = dt;
  }
  if (L < 16) {
    sden[0][rtS0 * 16 + L] = dent[0];
    sden[1][rtS1 * 16 + L] = dent[1];
  }
  __syncthreads();   // compute done: sST/skpref dead, union free; sden visible

  // publish m1 accO into exchange (stride 66: 2-way bank alias = free)
#pragma unroll
  for (int et = 0; et < 4; ++et)
#pragma unroll
    for (int r = 0; r < 4; ++r)
      u.exch[(rtS1 * 16 + g * 4 + r) * 66 + et * 16 + cL] = accO[1][et][r];
  __syncthreads();

  // finalize rows rtS0*16..+16: O = m0 + m1, scale by 1/(den0+den1+eps)
  float* op = out + off;
#pragma unroll
  for (int r = 0; r < 4; ++r) {
    int row = rtS0 * 16 + g * 4 + r;
    float inv = 1.f / (sden[0][row] + sden[1][row] + EPSV);
#pragma unroll
    for (int et = 0; et < 4; ++et) {
      float O = accO[0][et][r] + u.exch[row * 66 + et * 16 + cL];
      op[(size_t)row * DIM + et * 16 + cL] = O * inv;
    }
  }
}

extern "C" void kernel_launch(void* const* d_in, const int* in_sizes, int n_in,
                              void* d_out, int out_size, void* d_ws, size_t ws_size,
                              hipStream_t stream) {
  const float* q  = (const float*)d_in[0];
  const float* k  = (const float*)d_in[1];
  const float* qr = (const float*)d_in[2];
  const float* kr = (const float*)d_in[3];
  const float* v  = (const float*)d_in[4];
  float* out = (float*)d_out;
  float* ws  = (float*)d_ws;

  hipLaunchKernelGGL(pass_a, dim3(1024), dim3(256), 0, stream, k, kr, v, ws);
  hipLaunchKernelGGL(pass_b, dim3(264), dim3(256), 0, stream, ws);
  hipLaunchKernelGGL(pass_c, dim3(512), dim3(512), 0, stream, q, qr, ws, out);
}

// Round 10
// 139.026 us; speedup vs baseline: 1.4840x; 1.0494x over previous
//
#include <hip/hip_runtime.h>

#define SEQ 4096
#define DIM 64
#define CHUNK 128
#define NC 32
#define EPSV 1e-10f
#define KS_OFF 2097152   // float offset of ksum region (S region = 1024 chunks * 4096 bf16 = 8 MiB)

typedef __attribute__((ext_vector_type(8))) short s16x8;   // 8 bf16 (4 VGPRs)
typedef __attribute__((ext_vector_type(4))) float f32x4;   // MFMA C/D

__device__ __forceinline__ unsigned short f2bf(float f) {
  unsigned int u = __float_as_uint(f);
  u += 0x7FFF + ((u >> 16) & 1);          // RNE (inputs are finite)
  return (unsigned short)(u >> 16);
}
__device__ __forceinline__ float bf2f_lo(unsigned int x) { return __uint_as_float(x << 16); }

// native packed f32->bf16 (RNE), src0 -> low16, src1 -> high16
__device__ __forceinline__ unsigned int cvtpk(float lo, float hi) {
  unsigned int r;
  asm("v_cvt_pk_bf16_f32 %0, %1, %2" : "=v"(r) : "v"(lo), "v"(hi));
  return r;
}
__device__ __forceinline__ s16x8 pack8(float4 a, float4 b) {
  union { unsigned int u[4]; s16x8 v; } r;
  r.u[0] = cvtpk(a.x, a.y); r.u[1] = cvtpk(a.z, a.w);
  r.u[2] = cvtpk(b.x, b.y); r.u[3] = cvtpk(b.z, b.w);
  return r.v;
}

// Coalesced transposed gather: global [128][64] f32 row-major -> LDS T[d][j] bf16, stride 136.
template<bool SUM, int TPB>
__device__ __forceinline__ float gather_T(const float* __restrict__ gp,
                                          unsigned short* __restrict__ dst, int t) {
  int d = t & 63, grp = t >> 6;
  constexpr int GRPS = TPB / 64;
  constexpr int NI = 16 / GRPS;
  float s = 0.f;
#pragma unroll
  for (int i = 0; i < NI; ++i) {
    int j8 = grp + i * GRPS;
    const float* p = gp + (size_t)(j8 * 8) * DIM + d;
    float x[8];
#pragma unroll
    for (int u2 = 0; u2 < 8; ++u2) x[u2] = p[(size_t)u2 * DIM];
    if (SUM) {
#pragma unroll
      for (int u2 = 0; u2 < 8; ++u2) s += x[u2];
    }
    union { unsigned int u4[4]; s16x8 v; } seg;
#pragma unroll
    for (int u2 = 0; u2 < 4; ++u2) seg.u4[u2] = cvtpk(x[2 * u2], x[2 * u2 + 1]);
    *(s16x8*)&dst[d * 136 + j8 * 8] = seg.v;
  }
  return s;
}

// ---------------- Pass A (R1/R2 verified): S^T[e][d] via MFMA; store bf16 ----------------
__global__ __launch_bounds__(256) void pass_a(const float* __restrict__ k0,
                                              const float* __restrict__ k1,
                                              const float* __restrict__ v,
                                              float* __restrict__ ws) {
  __shared__ __align__(16) unsigned short skT[64 * 136];   // kT[d][j]
  __shared__ __align__(16) unsigned short svT[64 * 136];   // vT[e][j]
  __shared__ float spart[4][64];                           // fp32 ksum partials
  int bid = blockIdx.x;
  int m = bid >> 9, rem = bid & 511, hh = rem >> 5, c = rem & 31;
  const float* kp = (m ? k1 : k0) + (size_t)hh * SEQ * DIM + (size_t)c * CHUNK * DIM;
  const float* vp = v + (size_t)hh * SEQ * DIM + (size_t)c * CHUNK * DIM;
  int t = threadIdx.x;

  float s = gather_T<true, 256>(kp, skT, t);
  gather_T<false, 256>(vp, svT, t);
  spart[t >> 6][t & 63] = s;
  __syncthreads();

  // ksum[d] in full fp32 (pre-rounding values)
  if (t < 64)
    ws[KS_OFF + (size_t)bid * 64 + t] = spart[0][t] + spart[1][t] + spart[2][t] + spart[3][t];

  // MFMA: wave w -> e-tile w; A = vT (m=e), B = kT rows (k=j, n=d)
  int w = t >> 6, L = t & 63, g = L >> 4, cL = L & 15;
  f32x4 acc[4];
#pragma unroll
  for (int ct = 0; ct < 4; ++ct) acc[ct] = (f32x4){0.f, 0.f, 0.f, 0.f};
#pragma unroll
  for (int ks = 0; ks < 4; ++ks) {
    s16x8 aF = *(const s16x8*)&svT[(w * 16 + cL) * 136 + ks * 32 + g * 8];
#pragma unroll
    for (int ct = 0; ct < 4; ++ct) {
      s16x8 bF = *(const s16x8*)&skT[(ct * 16 + cL) * 136 + ks * 32 + g * 8];
      acc[ct] = __builtin_amdgcn_mfma_f32_16x16x32_bf16(aF, bF, acc[ct], 0, 0, 0);
    }
  }
  // C/D layout: col = cL (=d-local), row = g*4+r (=e-local); store bf16
  unsigned short* Sp = (unsigned short*)ws + (size_t)bid * 4096;
#pragma unroll
  for (int ct = 0; ct < 4; ++ct)
#pragma unroll
    for (int r = 0; r < 4; ++r)
      Sp[(size_t)(w * 16 + g * 4 + r) * 64 + ct * 16 + cL] = f2bf(acc[ct][r]);
}

// ---------------- Pass B (verified): exclusive prefix over chunks ----------------
__global__ __launch_bounds__(256) void pass_b(float* __restrict__ ws) {
  int t = threadIdx.x;
  if (blockIdx.x < 256) {
    int gid = blockIdx.x * 256 + t;            // [0, 65536)
    int mh = gid >> 11, de2 = gid & 2047;      // mh in [0,32)
    unsigned int* p = (unsigned int*)ws + (size_t)mh * NC * 2048 + de2;
    unsigned int x[NC];
#pragma unroll
    for (int c = 0; c < NC; ++c) x[c] = p[(size_t)c * 2048];
    float r0 = 0.f, r1 = 0.f;
#pragma unroll
    for (int c = 0; c < NC; ++c) {
      unsigned int xc = x[c];
      p[(size_t)c * 2048] = (unsigned int)f2bf(r0) | ((unsigned int)f2bf(r1) << 16);
      r0 += bf2f_lo(xc & 0xFFFFu);
      r1 += __uint_as_float(xc & 0xFFFF0000u);
    }
  } else {
    int gid = (blockIdx.x - 256) * 256 + t;    // [0, 2048)
    int mh = gid >> 6, d = gid & 63;
    float* p = ws + KS_OFF + (size_t)mh * NC * 64 + d;
    float x[NC];
#pragma unroll
    for (int c = 0; c < NC; ++c) x[c] = p[(size_t)c * 64];
    float run = 0.f;
#pragma unroll
    for (int c = 0; c < NC; ++c) {
      p[(size_t)c * 64] = run;
      run += x[c];
    }
  }
}

// ---------------- Pass C: 2 blocks per chunk, 4 waves each, wave-local m-combine ----------------
// Wave w of block-half b owns ONE rt (both m): rt = ((w&2)<<1) | (b ^ 3*(w&1)) ->
// b=0: {0,3,4,7}, b=1: {1,2,5,6} (per-block MFMA balanced: 216 each). Single accO/den per
// wave (O and den are sums over m for the SAME rows) -> no exch, no sden, ONE barrier total.
// 1024 blocks = 4 blocks/CU. Pairing swizzle keeps both halves of a chunk on one XCD.
__global__ __launch_bounds__(256, 4) void pass_c(const float* __restrict__ q0,
                                                 const float* __restrict__ q1,
                                                 const float* __restrict__ k0,
                                                 const float* __restrict__ k1,
                                                 const float* __restrict__ v,
                                                 const float* __restrict__ ws,
                                                 float* __restrict__ out) {
  __shared__ __align__(16) unsigned short svT[64 * 136];   // vT[e][j]  17408 B
  __shared__ __align__(16) unsigned short sST[2][64 * 72]; // S^T prefix per m, 18432 B
  __shared__ float skpref[2][64];                          // 512 B     (total 36.4 KB)

  // inverse pairing swizzle: blockIdx = (r*2+b)*8 + x, chunk ci = x*64 + r (x = XCD)
  int bidx = blockIdx.x;
  int x = bidx & 7, rb = bidx >> 3, b = rb & 1, rr = rb >> 1;
  int ci = x * 64 + rr;
  int hh = ci >> 5, c = ci & 31;
  int t = threadIdx.x;
  int w = t >> 6, L = t & 63, g = L >> 4, cL = L & 15;
  int rt = ((w & 2) << 1) | (b ^ (3 * (w & 1)));
  size_t off = (size_t)hh * SEQ * DIM + (size_t)c * CHUNK * DIM;

  gather_T<false, 256>(v + off, svT, t);
  // stage S^T prefix (bf16) + ksum-prefix for both m
#pragma unroll
  for (int half = 0; half < 2; ++half) {
    const unsigned short* Sp = (const unsigned short*)ws + (size_t)(half * 512 + ci) * 4096;
#pragma unroll
    for (int p2 = 0; p2 < 2; ++p2) {
      int idx = t + p2 * 256;
      *(s16x8*)&sST[half][(idx >> 3) * 72 + (idx & 7) * 8] = *(const s16x8*)&Sp[idx * 8];
    }
  }
  if (t < 64) {
    skpref[0][t] = ws[KS_OFF + (size_t)ci * 64 + t];
    skpref[1][t] = ws[KS_OFF + (size_t)(512 + ci) * 64 + t];
  }
  __syncthreads();                                         // the only barrier

  f32x4 accO[4];
#pragma unroll
  for (int e2 = 0; e2 < 4; ++e2) accO[e2] = (f32x4){0.f, 0.f, 0.f, 0.f};
  float dent = 0.f;
  s16x8 aq[2][2];

  // q loads + den(q . ksum_prefix) + inter O += q @ S_prefix (both m into same accO)
#pragma unroll
  for (int s2 = 0; s2 < 2; ++s2) {
    const float* qp = (s2 ? q1 : q0) + off;
    int row = rt * 16 + cL;
#pragma unroll
    for (int h = 0; h < 2; ++h) {
      const float* qb = qp + (size_t)row * DIM + h * 32 + g * 8;
      float4 a0 = *(const float4*)qb;
      float4 a1 = *(const float4*)(qb + 4);
      const float* kq = &skpref[s2][h * 32 + g * 8];
      dent += a0.x * kq[0] + a0.y * kq[1] + a0.z * kq[2] + a0.w * kq[3]
            + a1.x * kq[4] + a1.y * kq[5] + a1.z * kq[6] + a1.w * kq[7];
      aq[s2][h] = pack8(a0, a1);
    }
#pragma unroll
    for (int h = 0; h < 2; ++h)
#pragma unroll
      for (int et = 0; et < 4; ++et) {
        s16x8 bS = *(const s16x8*)&sST[s2][(et * 16 + cL) * 72 + h * 32 + g * 8];
        accO[et] = __builtin_amdgcn_mfma_f32_16x16x32_bf16(aq[s2][h], bS, accO[et], 0, 0, 0);
      }
  }

  // QK^T (swapped operands -> P^T: col=i=cL, row=j=g*4+r) + in-register transpose + PV
  {
    int srcA = cL + ((g & 1) << 5), srcB = srcA + 16;
    bool hiG = g >= 2;
#pragma unroll
    for (int s2 = 0; s2 < 2; ++s2) {
      const float* kpp = (s2 ? k1 : k0) + off;
      for (int ks = 0; ks <= (rt >> 1); ++ks) {
        unsigned int E0e, E1e;
        {
          int jt = 2 * ks;
          const float* kb = kpp + (size_t)(jt * 16 + cL) * DIM;
          float4 b0 = *(const float4*)(kb + g * 8);
          float4 b1 = *(const float4*)(kb + g * 8 + 4);
          float4 b2 = *(const float4*)(kb + 32 + g * 8);
          float4 b3 = *(const float4*)(kb + 32 + g * 8 + 4);
          s16x8 kf0 = pack8(b0, b1), kf1 = pack8(b2, b3);
          f32x4 C = (f32x4){0.f, 0.f, 0.f, 0.f};
          C = __builtin_amdgcn_mfma_f32_16x16x32_bf16(kf0, aq[s2][0], C, 0, 0, 0);
          C = __builtin_amdgcn_mfma_f32_16x16x32_bf16(kf1, aq[s2][1], C, 0, 0, 0);
          if (jt == rt) {                      // diagonal: zero j>i -> (g*4+r) > cL
#pragma unroll
            for (int r = 0; r < 4; ++r)
              if (g * 4 + r > cL) C[r] = 0.f;
          }
          dent += C[0] + C[1] + C[2] + C[3];
          E0e = cvtpk(C[0], C[1]); E1e = cvtpk(C[2], C[3]);
        }
        int S0o = 0, S1o = 0, S2o = 0, S3o = 0;
        if (2 * ks + 1 <= rt) {                // odd tile present (wave-uniform)
          int jt = 2 * ks + 1;
          const float* kb = kpp + (size_t)(jt * 16 + cL) * DIM;
          float4 b0 = *(const float4*)(kb + g * 8);
          float4 b1 = *(const float4*)(kb + g * 8 + 4);
          float4 b2 = *(const float4*)(kb + 32 + g * 8);
          float4 b3 = *(const float4*)(kb + 32 + g * 8 + 4);
          s16x8 kf0 = pack8(b0, b1), kf1 = pack8(b2, b3);
          f32x4 C = (f32x4){0.f, 0.f, 0.f, 0.f};
          C = __builtin_amdgcn_mfma_f32_16x16x32_bf16(kf0, aq[s2][0], C, 0, 0, 0);
          C = __builtin_amdgcn_mfma_f32_16x16x32_bf16(kf1, aq[s2][1], C, 0, 0, 0);
          if (jt == rt) {
#pragma unroll
            for (int r = 0; r < 4; ++r)
              if (g * 4 + r > cL) C[r] = 0.f;
          }
          dent += C[0] + C[1] + C[2] + C[3];
          unsigned int E0o = cvtpk(C[0], C[1]), E1o = cvtpk(C[2], C[3]);
          S0o = __shfl((int)E0o, srcA); S1o = __shfl((int)E1o, srcA);
          S2o = __shfl((int)E0o, srcB); S3o = __shfl((int)E1o, srcB);
        }
        int S0e = __shfl((int)E0e, srcA); int S1e = __shfl((int)E1e, srcA);
        int S2e = __shfl((int)E0e, srcB); int S3e = __shfl((int)E1e, srcB);
        union { int d4[4]; s16x8 v8; } ap;
        ap.d4[0] = hiG ? S0o : S0e;
        ap.d4[1] = hiG ? S1o : S1e;
        ap.d4[2] = hiG ? S2o : S2e;
        ap.d4[3] = hiG ? S3o : S3e;
#pragma unroll
        for (int et = 0; et < 4; ++et) {
          s16x8 bV = *(const s16x8*)&svT[(et * 16 + cL) * 136 + ks * 32 + g * 8];
          accO[et] = __builtin_amdgcn_mfma_f32_16x16x32_bf16(ap.v8, bV, accO[et], 0, 0, 0);
        }
      }
    }
  }

  // den: reduce over g (lane holds full row i=cL total), redistribute via shfl (no LDS)
  dent += __shfl_xor(dent, 16);
  dent += __shfl_xor(dent, 32);

  float* op = out + off;
#pragma unroll
  for (int r = 0; r < 4; ++r) {
    float dr = __shfl(dent, g * 4 + r);        // den of row rt*16 + g*4 + r
    float inv = 1.f / (dr + EPSV);
    int row = rt * 16 + g * 4 + r;
#pragma unroll
    for (int et = 0; et < 4; ++et)
      op[(size_t)row * DIM + et * 16 + cL] = accO[et][r] * inv;
  }
}

extern "C" void kernel_launch(void* const* d_in, const int* in_sizes, int n_in,
                              void* d_out, int out_size, void* d_ws, size_t ws_size,
                              hipStream_t stream) {
  const float* q  = (const float*)d_in[0];
  const float* k  = (const float*)d_in[1];
  const float* qr = (const float*)d_in[2];
  const float* kr = (const float*)d_in[3];
  const float* v  = (const float*)d_in[4];
  float* out = (float*)d_out;
  float* ws  = (float*)d_ws;

  hipLaunchKernelGGL(pass_a, dim3(1024), dim3(256), 0, stream, k, kr, v, ws);
  hipLaunchKernelGGL(pass_b, dim3(264), dim3(256), 0, stream, ws);
  hipLaunchKernelGGL(pass_c, dim3(1024), dim3(256), 0, stream, q, qr, k, kr, v, ws, out);
}